// Round 4
// baseline (334.292 us; speedup 1.0000x reference)
//
#include <hip/hip_runtime.h>
#include <hip/hip_bf16.h>

// GraphConvolution: out = relu( (W@x + b) @ adj^T + x ), B=4096, C=256, N=25.
// R4: register-resident fused kernel.
// Root cause of R1-R3's flat ~135us: compiler targeted max occupancy
// (VGPR_Count 44-68), sinking all prefetches -> K-loop was a serialized
// dependent-load latency chain. Fix: __launch_bounds__(256,2) => ~256-reg
// budget; ALL 32 W-fragments pinned in VGPRs (128 regs) loaded once per
// block; NB=8 batches per block amortize them; agg B-frags read direct from
// global x (no staging); double-buffered ys => 1 barrier/batch.

#define BATCH 4096
#define C 256
#define N 25
#define NB 8          // batches per block; grid = 4096/8 = 512
#define YSTR 264      // ys row stride (bf16): 528 B -> bank-conflict-safe b128 reads

typedef __bf16 bf16x8 __attribute__((ext_vector_type(8)));
typedef float f32x4 __attribute__((ext_vector_type(4)));
typedef float f32x4u __attribute__((ext_vector_type(4), aligned(4)));  // 4B-aligned vec load

// ---- prep: Wb = bf16(W); adjS[m] = rowsum(adj), 0 for m>=25 ----
__global__ void prep_kernel(const float* __restrict__ W, const float* __restrict__ adj,
                            __bf16* __restrict__ Wb, float* __restrict__ adjS) {
    int i = blockIdx.x * 256 + threadIdx.x;
    Wb[i] = (__bf16)W[i];
    if (blockIdx.x == 0 && threadIdx.x < 32) {
        float s = 0.f;
        if (threadIdx.x < N)
            for (int n = 0; n < N; ++n) s += adj[threadIdx.x * N + n];
        adjS[threadIdx.x] = s;
    }
}

__global__ __launch_bounds__(256, 2) void gcn_kernel(
    const float* __restrict__ x, const float* __restrict__ adj,
    const float* __restrict__ bias, const float* __restrict__ adjSg,
    const __bf16* __restrict__ Wb, float* __restrict__ out)
{
    __shared__ __align__(16) __bf16 adjbf[32 * 40];       // zero-padded adj, stride 40
    __shared__ __align__(16) __bf16 ys[2][32 * YSTR];     // double-buffered y tile
    __shared__ float biasS[C];

    const int tid = threadIdx.x;
    const int wv = tid >> 6, lane = tid & 63;
    const int quad = lane >> 4, l15 = lane & 15;
    const int o0 = wv * 64;            // wave's o-range (gemm) and c-range (agg)
    const int b0 = blockIdx.x * NB;

    // ---- stage adj (zero-padded 32x40) + bias ----
    for (int e = tid; e < N * N; e += 256) {
        int m = e / N, n = e - m * N;
        adjbf[m * 40 + n] = (__bf16)adj[e];
    }
    if (tid < N) {
        #pragma unroll
        for (int n = N; n < 32; ++n) adjbf[tid * 40 + n] = (__bf16)0.f;
    } else if (tid < 32) {
        #pragma unroll
        for (int n = 0; n < 32; ++n) adjbf[tid * 40 + n] = (__bf16)0.f;
    }
    biasS[tid] = bias[tid];

    // ---- pin ALL W A-fragments in registers (32 frags = 128 VGPRs), L2-hot ----
    bf16x8 af[8][4];
    #pragma unroll
    for (int kk = 0; kk < 8; ++kk)
        #pragma unroll
        for (int ot = 0; ot < 4; ++ot)
            af[kk][ot] = *(const bf16x8*)&Wb[(size_t)(o0 + ot * 16 + l15) * C + kk * 32 + quad * 8];

    const float aS0 = adjSg[l15];
    const float aS1 = adjSg[16 + l15];

    __syncthreads();  // adjbf/biasS ready

    const bf16x8 a0 = *(const bf16x8*)&adjbf[l15 * 40 + quad * 8];        // adj rows 0..15
    const bf16x8 a1 = *(const bf16x8*)&adjbf[(16 + l15) * 40 + quad * 8]; // rows 16..31 (zeroed >=25)

    #pragma unroll 1
    for (int bi = 0; bi < NB; ++bi) {
        const float* xb = x + (size_t)(b0 + bi) * (C * N);
        __bf16* ysp = ys[bi & 1];

        // ---- agg MFMA: D[m][c] = sum_n adj[m][n]*x[c][n]; B-frag direct from global x ----
        f32x4 yacc[4][2];
        #pragma unroll
        for (int ctl = 0; ctl < 4; ++ctl) {
            const int c = o0 + ctl * 16 + l15;
            bf16x8 xf;
            if (quad < 3) {          // n = quad*8 .. quad*8+7, all < 25
                f32x4u u = *(const f32x4u*)(xb + c * N + quad * 8);
                f32x4u v = *(const f32x4u*)(xb + c * N + quad * 8 + 4);
                xf[0] = (__bf16)u[0]; xf[1] = (__bf16)u[1]; xf[2] = (__bf16)u[2]; xf[3] = (__bf16)u[3];
                xf[4] = (__bf16)v[0]; xf[5] = (__bf16)v[1]; xf[6] = (__bf16)v[2]; xf[7] = (__bf16)v[3];
            } else {                 // n = 24..31: only 24 valid; adj k>=25 is zero anyway
                float u = xb[c * N + 24];
                xf[0] = (__bf16)u;
                #pragma unroll
                for (int j = 1; j < 8; ++j) xf[j] = (__bf16)0.f;
            }
            yacc[ctl][0] = __builtin_amdgcn_mfma_f32_16x16x32_bf16(a0, xf, (f32x4)0.f, 0, 0, 0);
            yacc[ctl][1] = __builtin_amdgcn_mfma_f32_16x16x32_bf16(a1, xf, (f32x4)0.f, 0, 0, 0);
        }

        // ---- C-layout -> ys[m][c] bf16 (write own c-range; buffer bi&1) ----
        #pragma unroll
        for (int ctl = 0; ctl < 4; ++ctl) {
            const int c = o0 + ctl * 16 + l15;
            #pragma unroll
            for (int mt = 0; mt < 2; ++mt)
                #pragma unroll
                for (int r = 0; r < 4; ++r)
                    ysp[(mt * 16 + quad * 4 + r) * YSTR + c] = (__bf16)yacc[ctl][mt][r];
        }
        __syncthreads();  // ys tile visible; prev buffer's reads already retired

        // ---- main GEMM: D[o][m] += W[o][c] * y[c][m]; af from REGISTERS ----
        f32x4 acc[4][2];
        #pragma unroll
        for (int ot = 0; ot < 4; ++ot) {
            acc[ot][0] = (f32x4)0.f;
            acc[ot][1] = (f32x4)0.f;
        }
        #pragma unroll
        for (int kk = 0; kk < 8; ++kk) {
            bf16x8 bfr0 = *(const bf16x8*)&ysp[l15 * YSTR + kk * 32 + quad * 8];
            bf16x8 bfr1 = *(const bf16x8*)&ysp[(16 + l15) * YSTR + kk * 32 + quad * 8];
            #pragma unroll
            for (int ot = 0; ot < 4; ++ot) {
                acc[ot][0] = __builtin_amdgcn_mfma_f32_16x16x32_bf16(af[kk][ot], bfr0, acc[ot][0], 0, 0, 0);
                acc[ot][1] = __builtin_amdgcn_mfma_f32_16x16x32_bf16(af[kk][ot], bfr1, acc[ot][1], 0, 0, 0);
            }
        }

        // ---- epilogue: + bias[o]*adjS[m] + x[o][m], relu ----
        float* outb = out + (size_t)(b0 + bi) * (C * N);
        #pragma unroll
        for (int ot = 0; ot < 4; ++ot)
            #pragma unroll
            for (int r = 0; r < 4; ++r) {
                const int o = o0 + ot * 16 + quad * 4 + r;
                const float bia = biasS[o];
                {   // mt=0: m = l15 < 16 always valid
                    const int m = l15;
                    float v = acc[ot][0][r] + bia * aS0 + xb[o * N + m];
                    outb[o * N + m] = v > 0.f ? v : 0.f;
                }
                if (l15 < N - 16) {  // mt=1: m = 16+l15 < 25
                    const int m = 16 + l15;
                    float v = acc[ot][1][r] + bia * aS1 + xb[o * N + m];
                    outb[o * N + m] = v > 0.f ? v : 0.f;
                }
            }
    }
}

extern "C" void kernel_launch(void* const* d_in, const int* in_sizes, int n_in,
                              void* d_out, int out_size, void* d_ws, size_t ws_size,
                              hipStream_t stream) {
    (void)in_sizes; (void)n_in; (void)out_size; (void)ws_size;
    const float* x    = (const float*)d_in[0];   // [4096, 256, 25]
    const float* adj  = (const float*)d_in[1];   // [25, 25]
    const float* W    = (const float*)d_in[2];   // [256, 256]
    const float* bias = (const float*)d_in[3];   // [256]
    float* out = (float*)d_out;

    unsigned char* ws = (unsigned char*)d_ws;
    __bf16* Wb   = (__bf16*)ws;                  // 131072 B
    float*  adjS = (float*)(ws + 131072);        // 128 B

    prep_kernel<<<(C * C) / 256, 256, 0, stream>>>(W, adj, Wb, adjS);
    gcn_kernel<<<BATCH / NB, 256, 0, stream>>>(x, adj, bias, adjS, Wb, out);
}

// Round 5
// 231.804 us; speedup vs baseline: 1.4421x; 1.4421x over previous
//
#include <hip/hip_runtime.h>
#include <hip/hip_bf16.h>

// GraphConvolution: out = relu( (W@x + b) @ adj^T + x ), B=4096, C=256, N=25.
// R5: gather-free kernel. Cross-round invariant: every structure so far cost
// ~50-100 cyc per vector-memory instruction because fragment/epilogue accesses
// were strided gathers (16-64 cache lines per instruction). This version makes
// EVERY global access fully coalesced:
//   - W pre-shuffled (prep) into per-wave fragment order -> af loads = 1KB contiguous
//   - x[b] in via coalesced float4 -> fp32 LDS; frags + residual from LDS
//   - out via LDS staging tile -> coalesced dwordx4 stores
// One block handles NB=8 batches (grid 512, 2 blocks/CU); af pinned in regs.

#define BATCH 4096
#define C 256
#define N 25
#define NB 8
#define XSTR 28      // xs fp32 row stride (112 B, 16B-aligned rows)
#define YSTR 264     // ys bf16 row stride (528 B, 16B-aligned rows)

typedef __bf16 bf16x8 __attribute__((ext_vector_type(8)));
typedef float f32x4 __attribute__((ext_vector_type(4)));

// ---- prep: Wshuf[frag][lane] = exact MFMA A-fragment bytes; adjS = rowsums ----
// frag f = ((wv*8 + kk)*4 + ot), lane l: element j = W[wv*64+ot*16+(l&15)][kk*32+(l>>4)*8+j]
__global__ void prep_kernel(const float* __restrict__ W, const float* __restrict__ adj,
                            bf16x8* __restrict__ Wshuf, float* __restrict__ adjS) {
    int i = blockIdx.x * 256 + threadIdx.x;       // 8192 = 128 frags x 64 lanes
    int f = i >> 6, l = i & 63;
    int wv = f >> 5, kk = (f >> 2) & 7, ot = f & 3;
    int quad = l >> 4, l15 = l & 15;
    int o = wv * 64 + ot * 16 + l15;
    int cb = kk * 32 + quad * 8;
    bf16x8 v;
    #pragma unroll
    for (int j = 0; j < 8; ++j) v[j] = (__bf16)W[o * C + cb + j];
    Wshuf[i] = v;
    if (blockIdx.x == 0 && threadIdx.x < 32) {
        float s = 0.f;
        if (threadIdx.x < N)
            for (int n = 0; n < N; ++n) s += adj[threadIdx.x * N + n];
        adjS[threadIdx.x] = s;
    }
}

__global__ __launch_bounds__(256, 2) void gcn_kernel(
    const float* __restrict__ x, const float* __restrict__ adj,
    const float* __restrict__ bias, const float* __restrict__ adjSg,
    const bf16x8* __restrict__ Wshuf, float* __restrict__ out)
{
    __shared__ __align__(16) float  xs[C * XSTR];   // 28672 B fp32 x tile
    __shared__ __align__(16) __bf16 ys[32 * YSTR];  // 16896 B bf16 y tile
    __shared__ __align__(16) __bf16 adjbf[32 * 40]; //  2560 B zero-padded adj
    __shared__ __align__(16) float  outS[C * N];    // 25600 B out staging
    __shared__ float biasS[C];                      //  1024 B   (total ~74.8 KB)

    const int tid = threadIdx.x;
    const int wv = tid >> 6, lane = tid & 63;
    const int quad = lane >> 4, l15 = lane & 15;
    const int o0 = wv * 64;                // wave's o-range (gemm) == c-range (agg)
    const int b0 = blockIdx.x * NB;

    // ---- one-time: adj staging (tiny gather), bias, pinned W fragments ----
    for (int e = tid; e < N * N; e += 256) {
        int m = e / N, n = e - m * N;
        adjbf[m * 40 + n] = (__bf16)adj[e];
    }
    if (tid < N) {
        #pragma unroll
        for (int n = N; n < 32; ++n) adjbf[tid * 40 + n] = (__bf16)0.f;
    } else if (tid < 32) {
        #pragma unroll
        for (int n = 0; n < 32; ++n) adjbf[tid * 40 + n] = (__bf16)0.f;
    }
    biasS[tid] = bias[tid];

    bf16x8 af[8][4];   // 128 VGPRs, loaded COALESCED (1KB contiguous per instr)
    #pragma unroll
    for (int kk = 0; kk < 8; ++kk)
        #pragma unroll
        for (int ot = 0; ot < 4; ++ot)
            af[kk][ot] = Wshuf[((wv * 8 + kk) * 4 + ot) * 64 + lane];

    const float aS0 = adjSg[l15];
    const float aS1 = adjSg[16 + l15];

    __syncthreads();   // adjbf/biasS ready

    const bf16x8 a0 = *(const bf16x8*)&adjbf[l15 * 40 + quad * 8];
    const bf16x8 a1 = *(const bf16x8*)&adjbf[(16 + l15) * 40 + quad * 8];

    #pragma unroll 1
    for (int bi = 0; bi < NB; ++bi) {
        const float* xb = x + (size_t)(b0 + bi) * (C * N);
        float* outb = out + (size_t)(b0 + bi) * (C * N);

        // ---- stage x[b]: coalesced float4 reads, scatter to xs (stride 28) ----
        #pragma unroll
        for (int q = 0; q < 7; ++q) {
            int i4 = q * 256 + tid;
            if (i4 < (C * N) / 4) {
                float4 v = ((const float4*)xb)[i4];
                int e = i4 * 4;
                int c = e / N, n = e - c * N;
                float fv[4] = {v.x, v.y, v.z, v.w};
                #pragma unroll
                for (int j = 0; j < 4; ++j) {
                    xs[c * XSTR + n] = fv[j];
                    ++n; if (n == N) { n = 0; ++c; }
                }
            }
        }
        __syncthreads();   // B1: xs ready

        // ---- agg MFMA: y[m][c] = sum_n adj[m][n]*x[c][n]; frags from LDS ----
        f32x4 yacc[4][2];
        #pragma unroll
        for (int ctl = 0; ctl < 4; ++ctl) {
            const int c = o0 + ctl * 16 + l15;
            bf16x8 xf;
            if (quad < 3) {   // n = quad*8..quad*8+7 all < 25; 16B-aligned LDS reads
                f32x4 u = *(const f32x4*)&xs[c * XSTR + quad * 8];
                f32x4 w = *(const f32x4*)&xs[c * XSTR + quad * 8 + 4];
                xf[0] = (__bf16)u[0]; xf[1] = (__bf16)u[1]; xf[2] = (__bf16)u[2]; xf[3] = (__bf16)u[3];
                xf[4] = (__bf16)w[0]; xf[5] = (__bf16)w[1]; xf[6] = (__bf16)w[2]; xf[7] = (__bf16)w[3];
            } else {          // n = 24..31: only 24 valid; rest zero (adj k>=25 is 0 too)
                float u = xs[c * XSTR + 24];
                xf[0] = (__bf16)u;
                #pragma unroll
                for (int j = 1; j < 8; ++j) xf[j] = (__bf16)0.f;
            }
            yacc[ctl][0] = __builtin_amdgcn_mfma_f32_16x16x32_bf16(a0, xf, (f32x4)0.f, 0, 0, 0);
            yacc[ctl][1] = __builtin_amdgcn_mfma_f32_16x16x32_bf16(a1, xf, (f32x4)0.f, 0, 0, 0);
        }
        // C-layout (col=l15 -> c, row=quad*4+r -> m) -> ys[m][c]
        #pragma unroll
        for (int ctl = 0; ctl < 4; ++ctl) {
            const int c = o0 + ctl * 16 + l15;
            #pragma unroll
            for (int mt = 0; mt < 2; ++mt)
                #pragma unroll
                for (int r = 0; r < 4; ++r)
                    ys[(mt * 16 + quad * 4 + r) * YSTR + c] = (__bf16)yacc[ctl][mt][r];
        }
        __syncthreads();   // B2: ys ready

        // ---- main GEMM: out[o][m] += W[o][c]*y[c][m]; af from registers ----
        f32x4 acc[4][2];
        #pragma unroll
        for (int ot = 0; ot < 4; ++ot) { acc[ot][0] = (f32x4)0.f; acc[ot][1] = (f32x4)0.f; }
        #pragma unroll
        for (int kk = 0; kk < 8; ++kk) {
            bf16x8 bfr0 = *(const bf16x8*)&ys[l15 * YSTR + kk * 32 + quad * 8];
            bf16x8 bfr1 = *(const bf16x8*)&ys[(16 + l15) * YSTR + kk * 32 + quad * 8];
            #pragma unroll
            for (int ot = 0; ot < 4; ++ot) {
                acc[ot][0] = __builtin_amdgcn_mfma_f32_16x16x32_bf16(af[kk][ot], bfr0, acc[ot][0], 0, 0, 0);
                acc[ot][1] = __builtin_amdgcn_mfma_f32_16x16x32_bf16(af[kk][ot], bfr1, acc[ot][1], 0, 0, 0);
            }
        }

        // ---- epilogue into LDS staging tile (residual from xs LDS) ----
        #pragma unroll
        for (int ot = 0; ot < 4; ++ot)
            #pragma unroll
            for (int r = 0; r < 4; ++r) {
                const int o = o0 + ot * 16 + quad * 4 + r;
                const float bia = biasS[o];
                {   // m = l15 (<16, always valid)
                    const int m = l15;
                    float v = acc[ot][0][r] + bia * aS0 + xs[o * XSTR + m];
                    outS[o * N + m] = v > 0.f ? v : 0.f;
                }
                if (l15 < N - 16) {   // m = 16+l15 < 25
                    const int m = 16 + l15;
                    float v = acc[ot][1][r] + bia * aS1 + xs[o * XSTR + m];
                    outS[o * N + m] = v > 0.f ? v : 0.f;
                }
            }
        __syncthreads();   // B3: outS ready

        // ---- coalesced dwordx4 store of the whole out tile ----
        #pragma unroll
        for (int q = 0; q < 7; ++q) {
            int i4 = q * 256 + tid;
            if (i4 < (C * N) / 4)
                ((float4*)outb)[i4] = ((const float4*)outS)[i4];
        }
    }
}

extern "C" void kernel_launch(void* const* d_in, const int* in_sizes, int n_in,
                              void* d_out, int out_size, void* d_ws, size_t ws_size,
                              hipStream_t stream) {
    (void)in_sizes; (void)n_in; (void)out_size; (void)ws_size;
    const float* x    = (const float*)d_in[0];   // [4096, 256, 25]
    const float* adj  = (const float*)d_in[1];   // [25, 25]
    const float* W    = (const float*)d_in[2];   // [256, 256]
    const float* bias = (const float*)d_in[3];   // [256]
    float* out = (float*)d_out;

    unsigned char* ws = (unsigned char*)d_ws;
    bf16x8* Wshuf = (bf16x8*)ws;                 // 131072 B (128 frags x 64 lanes x 16 B)
    float*  adjS  = (float*)(ws + 131072);       // 128 B

    prep_kernel<<<32, 256, 0, stream>>>(W, adj, Wshuf, adjS);
    gcn_kernel<<<BATCH / NB, 256, 0, stream>>>(x, adj, bias, adjS, Wshuf, out);
}